// Round 2
// baseline (894.971 us; speedup 1.0000x reference)
//
#include <hip/hip_runtime.h>

// NRI MLP decoder, single step, fp32.
// Shapes: B=8, N=32, T=256, D=4, E=992 (=32*31), K=2, H=64, M=64, NH=128.
// inputs (B,N,T,D); x[b,t,n,:] = inputs[b,n,t,:].
// Edge e: receiver i = e/31, jj = e%31, sender j = jj<i ? jj : jj+1.
// h1 = relu(x[j]@W1[k][0:4] + x[i]@W1[k][4:8] + b1[k])   (senders first in concat)
// msg = relu(h1@W2[k] + b2[k]);  agg[i] += msg * g[e,k]
// aug=[x,agg] -> relu(@Wo1+bo1) -> relu(@Wo2+bo2) -> @Wo3+bo3 ; out = x + pred
// out0: (B,N,T-1,D) = 261120 floats ; out1: (B,E,K) = 15872 floats.

#define N_NODES 32
#define T_LEN   256

__global__ __launch_bounds__(256, 2)
void nri_fused(const float* __restrict__ inputs,
               const float* __restrict__ rel_graph,
               const float* __restrict__ W1,  const float* __restrict__ b1,
               const float* __restrict__ W2,  const float* __restrict__ b2,
               const float* __restrict__ Wo1, const float* __restrict__ bo1,
               const float* __restrict__ Wo2, const float* __restrict__ bo2,
               const float* __restrict__ Wo3, const float* __restrict__ bo3,
               float* __restrict__ out)
{
    // LDS carve (floats): 128 x | 1984 g | 1024 W1 | 128 b1 | 2048 S | 2048 R | 7936 h1
    // phase-C overlays S/R/h1: agg 32x66, h 32x129, p2 32x129
    __shared__ float smem[15296];          // 61184 bytes -> 2 blocks/CU
    float* x_l  = smem;                    // 32*4
    float* g_l  = smem + 128;              // 1984
    float* w1_l = smem + 128 + 1984;       // 1024
    float* b1_l = w1_l + 1024;             // 128
    float* S    = b1_l + 128;              // 32*64
    float* R    = S + 2048;                // 32*64
    float* h1   = R + 2048;                // 124*64
    float* agg_l = S;                      // 32*66  = 2112
    float* h_l   = S + 2112;               // 32*129 = 4128
    float* p2_l  = h_l + 4128;             // 32*129 = 4128  (ends within h1 region)

    const int tid = threadIdx.x;
    const int bt  = blockIdx.x;
    const int b   = bt >> 8;               // T = 256
    const int t   = bt & 255;

    // ---- stage x, g, W1, b1 ----
    if (tid < N_NODES) {
        const float4 v = *reinterpret_cast<const float4*>(
            inputs + ((size_t)(b * N_NODES + tid) * T_LEN + t) * 4);
        reinterpret_cast<float4*>(x_l)[tid] = v;
    }
    for (int idx = tid; idx < 1984; idx += 256) g_l[idx]  = rel_graph[idx];
    for (int idx = tid; idx < 1024; idx += 256) w1_l[idx] = W1[idx];
    if (tid < 128) b1_l[tid] = b1[tid];
    __syncthreads();

    const int w = tid >> 6;   // wave 0..3
    const int m = tid & 63;   // output column of W2

    float agg_reg[8];
    #pragma unroll
    for (int i = 0; i < 8; ++i) agg_reg[i] = 0.f;

    #pragma unroll
    for (int k = 0; k < 2; ++k) {
        // ---- per-node projections S (sender part + b1) and R (receiver part) ----
        for (int idx = tid; idx < 2048; idx += 256) {
            const int n = idx >> 6, kk = idx & 63;
            const float* xr = x_l + n * 4;
            const float* wp = w1_l + k * 512 + kk;
            float s = b1_l[k * 64 + kk];
            float r = 0.f;
            #pragma unroll
            for (int d = 0; d < 4; ++d) {
                s = fmaf(xr[d], wp[d * 64], s);
                r = fmaf(xr[d], wp[(4 + d) * 64], r);
            }
            S[idx] = s;
            R[idx] = r;
        }
        // W2 column m into registers
        float w2col[64];
        #pragma unroll
        for (int kk = 0; kk < 64; ++kk) w2col[kk] = W2[k * 4096 + kk * 64 + m];
        const float b2v = b2[k * 64 + m];
        __syncthreads();

        #pragma unroll
        for (int tile = 0; tile < 8; ++tile) {
            const int e0 = tile * 124;                  // 4 receivers per tile
            // ---- h1 tile: 124 edges x 64, float4-wise ----
            for (int idx = tid; idx < 124 * 16; idx += 256) {
                const int el = idx >> 4;
                const int kq = idx & 15;
                const int e  = e0 + el;
                const int i  = e / 31;
                const int jj = e - i * 31;
                const int j  = (jj < i) ? jj : jj + 1;
                const float4 sv = reinterpret_cast<const float4*>(S + j * 64)[kq];
                const float4 rv = reinterpret_cast<const float4*>(R + i * 64)[kq];
                float4 hv;
                hv.x = fmaxf(sv.x + rv.x, 0.f);
                hv.y = fmaxf(sv.y + rv.y, 0.f);
                hv.z = fmaxf(sv.z + rv.z, 0.f);
                hv.w = fmaxf(sv.w + rv.w, 0.f);
                reinterpret_cast<float4*>(h1 + el * 64)[kq] = hv;
            }
            __syncthreads();
            // ---- GEMV: wave w owns receiver n = tile*4 + w (31 edges) ----
            {
                const int ebase = e0 + w * 31;
                float accA = agg_reg[tile];
                for (int ee = 0; ee < 31; ++ee) {
                    const float4* hp =
                        reinterpret_cast<const float4*>(h1 + (w * 31 + ee) * 64);
                    float a0 = 0.f, a1 = 0.f, a2 = 0.f, a3 = 0.f;
                    #pragma unroll
                    for (int kq = 0; kq < 16; ++kq) {
                        const float4 h4 = hp[kq];          // broadcast read
                        a0 = fmaf(h4.x, w2col[4 * kq + 0], a0);
                        a1 = fmaf(h4.y, w2col[4 * kq + 1], a1);
                        a2 = fmaf(h4.z, w2col[4 * kq + 2], a2);
                        a3 = fmaf(h4.w, w2col[4 * kq + 3], a3);
                    }
                    float msg = fmaxf((a0 + a1) + (a2 + a3) + b2v, 0.f);
                    accA = fmaf(msg, g_l[(ebase + ee) * 2 + k], accA);
                }
                agg_reg[tile] = accA;
            }
            __syncthreads();
        }
    }

    // ---- dump agg registers to LDS (each (n,m) owned by exactly one lane) ----
    #pragma unroll
    for (int tile = 0; tile < 8; ++tile) {
        agg_l[(tile * 4 + w) * 66 + m] = agg_reg[tile];
    }
    __syncthreads();

    // ---- node MLP: 32 rows of aug(68) -> 128 -> 128 -> 4 ----
    const int c  = tid >> 3;   // col group: cols c*4 .. c*4+3
    const int rg = tid & 7;    // row group: rows rg*4 .. rg*4+3 (stride-4 interleave)

    // layer 1
    {
        float acc[4][4];
        #pragma unroll
        for (int i = 0; i < 4; ++i)
            #pragma unroll
            for (int j = 0; j < 4; ++j) acc[i][j] = 0.f;
        #pragma unroll
        for (int d = 0; d < 4; ++d) {      // x part
            const float4 wv = *reinterpret_cast<const float4*>(Wo1 + d * 128 + c * 4);
            #pragma unroll
            for (int i = 0; i < 4; ++i) {
                const float av = x_l[(rg * 4 + i) * 4 + d];
                acc[i][0] = fmaf(av, wv.x, acc[i][0]);
                acc[i][1] = fmaf(av, wv.y, acc[i][1]);
                acc[i][2] = fmaf(av, wv.z, acc[i][2]);
                acc[i][3] = fmaf(av, wv.w, acc[i][3]);
            }
        }
        for (int d = 0; d < 64; ++d) {     // agg part
            const float4 wv = *reinterpret_cast<const float4*>(Wo1 + (4 + d) * 128 + c * 4);
            #pragma unroll
            for (int i = 0; i < 4; ++i) {
                const float av = agg_l[(rg * 4 + i) * 66 + d];
                acc[i][0] = fmaf(av, wv.x, acc[i][0]);
                acc[i][1] = fmaf(av, wv.y, acc[i][1]);
                acc[i][2] = fmaf(av, wv.z, acc[i][2]);
                acc[i][3] = fmaf(av, wv.w, acc[i][3]);
            }
        }
        const float4 bv = *reinterpret_cast<const float4*>(bo1 + c * 4);
        #pragma unroll
        for (int i = 0; i < 4; ++i) {
            float* hr = h_l + (rg * 4 + i) * 129 + c * 4;
            hr[0] = fmaxf(acc[i][0] + bv.x, 0.f);
            hr[1] = fmaxf(acc[i][1] + bv.y, 0.f);
            hr[2] = fmaxf(acc[i][2] + bv.z, 0.f);
            hr[3] = fmaxf(acc[i][3] + bv.w, 0.f);
        }
    }
    __syncthreads();

    // layer 2
    {
        float acc[4][4];
        #pragma unroll
        for (int i = 0; i < 4; ++i)
            #pragma unroll
            for (int j = 0; j < 4; ++j) acc[i][j] = 0.f;
        for (int d = 0; d < 128; ++d) {
            const float4 wv = *reinterpret_cast<const float4*>(Wo2 + d * 128 + c * 4);
            #pragma unroll
            for (int i = 0; i < 4; ++i) {
                const float av = h_l[(rg * 4 + i) * 129 + d];
                acc[i][0] = fmaf(av, wv.x, acc[i][0]);
                acc[i][1] = fmaf(av, wv.y, acc[i][1]);
                acc[i][2] = fmaf(av, wv.z, acc[i][2]);
                acc[i][3] = fmaf(av, wv.w, acc[i][3]);
            }
        }
        const float4 bv = *reinterpret_cast<const float4*>(bo2 + c * 4);
        #pragma unroll
        for (int i = 0; i < 4; ++i) {
            float* pr = p2_l + (rg * 4 + i) * 129 + c * 4;
            pr[0] = fmaxf(acc[i][0] + bv.x, 0.f);
            pr[1] = fmaxf(acc[i][1] + bv.y, 0.f);
            pr[2] = fmaxf(acc[i][2] + bv.z, 0.f);
            pr[3] = fmaxf(acc[i][3] + bv.w, 0.f);
        }
    }
    __syncthreads();

    // layer 3 + residual + store (skip t == 255)
    if (tid < 128) {
        const int r  = tid >> 2;
        const int dd = tid & 3;
        float a0 = 0.f, a1 = 0.f, a2 = 0.f, a3 = 0.f;
        const float* pr = p2_l + r * 129;
        for (int d = 0; d < 128; d += 4) {
            a0 = fmaf(pr[d + 0], Wo3[(d + 0) * 4 + dd], a0);
            a1 = fmaf(pr[d + 1], Wo3[(d + 1) * 4 + dd], a1);
            a2 = fmaf(pr[d + 2], Wo3[(d + 2) * 4 + dd], a2);
            a3 = fmaf(pr[d + 3], Wo3[(d + 3) * 4 + dd], a3);
        }
        const float pred = ((a0 + a1) + (a2 + a3)) + bo3[dd];
        if (t < T_LEN - 1) {
            out[((size_t)(b * N_NODES + r) * (T_LEN - 1) + t) * 4 + dd] =
                x_l[r * 4 + dd] + pred;
        }
    }
}

__global__ void copy_relgraph(const float* __restrict__ g, float* __restrict__ out2)
{
    const int idx = blockIdx.x * 256 + threadIdx.x;
    if (idx < 15872) out2[idx] = g[idx % 1984];
}

extern "C" void kernel_launch(void* const* d_in, const int* in_sizes, int n_in,
                              void* d_out, int out_size, void* d_ws, size_t ws_size,
                              hipStream_t stream)
{
    (void)in_sizes; (void)n_in; (void)d_ws; (void)ws_size; (void)out_size;
    const float* inputs    = (const float*)d_in[0];
    // d_in[1] rel_rec, d_in[2] rel_send: structure is implicit (i=e/31), unused
    const float* rel_graph = (const float*)d_in[3];
    const float* W1  = (const float*)d_in[4];
    const float* b1  = (const float*)d_in[5];
    const float* W2  = (const float*)d_in[6];
    const float* b2  = (const float*)d_in[7];
    const float* Wo1 = (const float*)d_in[8];
    const float* bo1 = (const float*)d_in[9];
    const float* Wo2 = (const float*)d_in[10];
    const float* bo2 = (const float*)d_in[11];
    const float* Wo3 = (const float*)d_in[12];
    const float* bo3 = (const float*)d_in[13];
    float* out = (float*)d_out;

    nri_fused<<<2048, 256, 0, stream>>>(inputs, rel_graph, W1, b1, W2, b2,
                                        Wo1, bo1, Wo2, bo2, Wo3, bo3, out);
    // rel_graph_out: (B,E,K) broadcast copy, appended after 8*32*255*4 floats
    copy_relgraph<<<62, 256, 0, stream>>>(rel_graph, out + 261120);
}

// Round 3
// 625.439 us; speedup vs baseline: 1.4309x; 1.4309x over previous
//
#include <hip/hip_runtime.h>

// NRI MLP decoder, single step, fp32. B=8, N=32, T=256, D=4, E=992, K=2, H=64, M=64, NH=128.
// Edge e: receiver i=e/31, jj=e%31, sender j = jj<i ? jj : jj+1.
// h1 = relu(S[j] + R[i]) with S = x@W1[k][0:4]+b1 (senders first), R = x@W1[k][4:8].
// msg = relu(h1@W2[k]+b2[k]); agg[i] += msg*g[e,k]
// aug=[x,agg] -> relu(@Wo1+bo1) -> relu(@Wo2+bo2) -> @Wo3+bo3; out = x + pred.
// out0: (B,N,255,4) = 261120 floats; out1: (B,E,K) = 15872 floats.
//
// Edge GEMM: receiver-aligned 32-row tiles (row 31 = zero pad, g masked), h1 stored
// TRANSPOSED h1T[kk][el]. Wave = (receiver, m-half); lane = 4 edges x 4 m. Per kk:
// 2x ds_read_b128 (conflict-free) -> 16 FMA. LDS 49.1KB -> 3 blocks/CU.

__global__ __launch_bounds__(256, 3)
void nri_fused(const float* __restrict__ inputs,
               const float* __restrict__ rgraph,
               const float* __restrict__ W1,  const float* __restrict__ b1,
               const float* __restrict__ W2,  const float* __restrict__ b2,
               const float* __restrict__ Wo1, const float* __restrict__ bo1,
               const float* __restrict__ Wo2, const float* __restrict__ bo2,
               const float* __restrict__ Wo3, const float* __restrict__ bo3,
               float* __restrict__ out)
{
    // floats: [x 128][agg 32*65=2080][S 32*68=2176][w2 4096][h1T 2*2048=4096] = 12576 (49.1KB)
    // node-MLP overlay: h_l 32*129 @2208, p2_l 32*129 @6336 (x, agg preserved)
    __shared__ float smem[12576];
    float* x_l  = smem;
    float* agg  = smem + 128;
    float* S    = smem + 2208;
    float* w2_l = smem + 4384;
    float* h1T  = smem + 8480;
    float* h_l  = smem + 2208;
    float* p2_l = smem + 6336;

    const int tid = threadIdx.x;
    const int b   = blockIdx.x >> 8;
    const int t   = blockIdx.x & 255;

    if (tid < 32) {
        reinterpret_cast<float4*>(x_l)[tid] =
            *reinterpret_cast<const float4*>(inputs + ((size_t)(b * 32 + tid) * 256 + t) * 4);
    }
    for (int idx = tid; idx < 2080; idx += 256) agg[idx] = 0.f;

    const int wv   = tid >> 6;
    const int lane = tid & 63;
    const int r    = lane & 7;     // edge-group (4 edges)
    const int c    = lane >> 3;    // m-group (4 cols)
    // construction mapping: 2 tiles x 32 el x 4 kk4a-slots
    const int tauC = tid >> 7;
    const int el   = tid & 31;
    const int k4a  = (tid >> 5) & 3;
    // gemv mapping
    const int tauG = wv >> 1;
    const int m0   = (wv & 1) << 5;

    __syncthreads();

    for (int k = 0; k < 2; ++k) {
        // ---- stage S (sender proj + bias) and W2[k] ----
        for (int idx = tid; idx < 2048; idx += 256) {
            const int j = idx >> 6, kk = idx & 63;
            const float4 xj = reinterpret_cast<const float4*>(x_l)[j];
            const float* wp = W1 + k * 512 + kk;
            float s = b1[k * 64 + kk];
            s = fmaf(xj.x, wp[0],   s);
            s = fmaf(xj.y, wp[64],  s);
            s = fmaf(xj.z, wp[128], s);
            s = fmaf(xj.w, wp[192], s);
            S[j * 68 + kk] = s;
        }
        for (int idx = tid; idx < 1024; idx += 256)
            reinterpret_cast<float4*>(w2_l)[idx] =
                reinterpret_cast<const float4*>(W2 + k * 4096)[idx];
        __syncthreads();

        for (int rho = 0; rho < 16; ++rho) {
            // ---- build h1T for receivers 2rho+tauC (R recomputed inline, L1-hot W1) ----
            {
                float* hb = h1T + tauC * 2048;
                const int i = 2 * rho + tauC;
                if (el == 31) {
                    #pragma unroll
                    for (int gq = 0; gq < 4; ++gq) {
                        const int kkb = (k4a + 4 * gq) * 4;
                        hb[(kkb + 0) * 32 + 31] = 0.f;
                        hb[(kkb + 1) * 32 + 31] = 0.f;
                        hb[(kkb + 2) * 32 + 31] = 0.f;
                        hb[(kkb + 3) * 32 + 31] = 0.f;
                    }
                } else {
                    const int j = (el < i) ? el : el + 1;
                    const float4 xi = reinterpret_cast<const float4*>(x_l)[i];
                    const float* w1r = W1 + k * 512 + 256;   // receiver rows 4..7
                    #pragma unroll
                    for (int gq = 0; gq < 4; ++gq) {
                        const int kkb = (k4a + 4 * gq) * 4;
                        const float4 s4 = *reinterpret_cast<const float4*>(S + j * 68 + kkb);
                        const float4 wa = *reinterpret_cast<const float4*>(w1r + kkb);
                        const float4 wbv = *reinterpret_cast<const float4*>(w1r + 64 + kkb);
                        const float4 wc = *reinterpret_cast<const float4*>(w1r + 128 + kkb);
                        const float4 wd = *reinterpret_cast<const float4*>(w1r + 192 + kkb);
                        float hx = s4.x;
                        hx = fmaf(xi.x, wa.x, hx); hx = fmaf(xi.y, wbv.x, hx);
                        hx = fmaf(xi.z, wc.x, hx); hx = fmaf(xi.w, wd.x, hx);
                        float hy = s4.y;
                        hy = fmaf(xi.x, wa.y, hy); hy = fmaf(xi.y, wbv.y, hy);
                        hy = fmaf(xi.z, wc.y, hy); hy = fmaf(xi.w, wd.y, hy);
                        float hz = s4.z;
                        hz = fmaf(xi.x, wa.z, hz); hz = fmaf(xi.y, wbv.z, hz);
                        hz = fmaf(xi.z, wc.z, hz); hz = fmaf(xi.w, wd.z, hz);
                        float hw = s4.w;
                        hw = fmaf(xi.x, wa.w, hw); hw = fmaf(xi.y, wbv.w, hw);
                        hw = fmaf(xi.z, wc.w, hw); hw = fmaf(xi.w, wd.w, hw);
                        hb[(kkb + 0) * 32 + el] = fmaxf(hx, 0.f);
                        hb[(kkb + 1) * 32 + el] = fmaxf(hy, 0.f);
                        hb[(kkb + 2) * 32 + el] = fmaxf(hz, 0.f);
                        hb[(kkb + 3) * 32 + el] = fmaxf(hw, 0.f);
                    }
                }
            }
            // epilogue operands prefetched under construction (global, L1-hot)
            const int i = 2 * rho + tauG;
            const float4 b2v = *reinterpret_cast<const float4*>(b2 + k * 64 + m0 + 4 * c);
            float ge[4];
            #pragma unroll
            for (int q = 0; q < 4; ++q) {
                const int row = 4 * r + q;
                ge[q] = (row < 31) ? rgraph[(31 * i + row) * 2 + k] : 0.f;
            }
            __syncthreads();

            // ---- 32x32 GEMV tile, 4x4 per lane ----
            float acc[4][4];
            #pragma unroll
            for (int q = 0; q < 4; ++q)
                #pragma unroll
                for (int j2 = 0; j2 < 4; ++j2) acc[q][j2] = 0.f;

            const float* ha = h1T + tauG * 2048 + 4 * r;
            const float* wb = w2_l + m0 + 4 * c;
            #pragma unroll 8
            for (int kk = 0; kk < 64; ++kk) {
                const float4 a4 = *reinterpret_cast<const float4*>(ha + kk * 32);
                const float4 b4 = *reinterpret_cast<const float4*>(wb + kk * 64);
                acc[0][0] = fmaf(a4.x, b4.x, acc[0][0]);
                acc[0][1] = fmaf(a4.x, b4.y, acc[0][1]);
                acc[0][2] = fmaf(a4.x, b4.z, acc[0][2]);
                acc[0][3] = fmaf(a4.x, b4.w, acc[0][3]);
                acc[1][0] = fmaf(a4.y, b4.x, acc[1][0]);
                acc[1][1] = fmaf(a4.y, b4.y, acc[1][1]);
                acc[1][2] = fmaf(a4.y, b4.z, acc[1][2]);
                acc[1][3] = fmaf(a4.y, b4.w, acc[1][3]);
                acc[2][0] = fmaf(a4.z, b4.x, acc[2][0]);
                acc[2][1] = fmaf(a4.z, b4.y, acc[2][1]);
                acc[2][2] = fmaf(a4.z, b4.z, acc[2][2]);
                acc[2][3] = fmaf(a4.z, b4.w, acc[2][3]);
                acc[3][0] = fmaf(a4.w, b4.x, acc[3][0]);
                acc[3][1] = fmaf(a4.w, b4.y, acc[3][1]);
                acc[3][2] = fmaf(a4.w, b4.z, acc[3][2]);
                acc[3][3] = fmaf(a4.w, b4.w, acc[3][3]);
            }

            // msg = relu(acc + b2); part = sum_q msg*g ; reduce over 8 r-lanes
            float part[4];
            const float bb0 = b2v.x, bb1 = b2v.y, bb2 = b2v.z, bb3 = b2v.w;
            #pragma unroll
            for (int j2 = 0; j2 < 4; ++j2) part[j2] = 0.f;
            #pragma unroll
            for (int q = 0; q < 4; ++q) {
                part[0] = fmaf(fmaxf(acc[q][0] + bb0, 0.f), ge[q], part[0]);
                part[1] = fmaf(fmaxf(acc[q][1] + bb1, 0.f), ge[q], part[1]);
                part[2] = fmaf(fmaxf(acc[q][2] + bb2, 0.f), ge[q], part[2]);
                part[3] = fmaf(fmaxf(acc[q][3] + bb3, 0.f), ge[q], part[3]);
            }
            #pragma unroll
            for (int j2 = 0; j2 < 4; ++j2) {
                part[j2] += __shfl_xor(part[j2], 1);
                part[j2] += __shfl_xor(part[j2], 2);
                part[j2] += __shfl_xor(part[j2], 4);
            }
            if (r == 0) {
                #pragma unroll
                for (int j2 = 0; j2 < 4; ++j2)
                    agg[i * 65 + m0 + 4 * c + j2] += part[j2];
            }
            __syncthreads();
        }
    }

    // ---- node MLP: 32 rows of aug(68) -> 128 -> 128 -> 4 ----
    const int cc = tid >> 3;   // col group: cols cc*4..+3
    const int rgp = tid & 7;   // row group: rows rgp*4..+3 (stride-4 interleave)

    // layer 1
    {
        float acc[4][4];
        #pragma unroll
        for (int i = 0; i < 4; ++i)
            #pragma unroll
            for (int j = 0; j < 4; ++j) acc[i][j] = 0.f;
        #pragma unroll
        for (int d = 0; d < 4; ++d) {      // x part
            const float4 wv4 = *reinterpret_cast<const float4*>(Wo1 + d * 128 + cc * 4);
            #pragma unroll
            for (int i = 0; i < 4; ++i) {
                const float av = x_l[(rgp * 4 + i) * 4 + d];
                acc[i][0] = fmaf(av, wv4.x, acc[i][0]);
                acc[i][1] = fmaf(av, wv4.y, acc[i][1]);
                acc[i][2] = fmaf(av, wv4.z, acc[i][2]);
                acc[i][3] = fmaf(av, wv4.w, acc[i][3]);
            }
        }
        for (int d = 0; d < 64; ++d) {     // agg part
            const float4 wv4 = *reinterpret_cast<const float4*>(Wo1 + (4 + d) * 128 + cc * 4);
            #pragma unroll
            for (int i = 0; i < 4; ++i) {
                const float av = agg[(rgp * 4 + i) * 65 + d];
                acc[i][0] = fmaf(av, wv4.x, acc[i][0]);
                acc[i][1] = fmaf(av, wv4.y, acc[i][1]);
                acc[i][2] = fmaf(av, wv4.z, acc[i][2]);
                acc[i][3] = fmaf(av, wv4.w, acc[i][3]);
            }
        }
        const float4 bv = *reinterpret_cast<const float4*>(bo1 + cc * 4);
        #pragma unroll
        for (int i = 0; i < 4; ++i) {
            float* hr = h_l + (rgp * 4 + i) * 129 + cc * 4;
            hr[0] = fmaxf(acc[i][0] + bv.x, 0.f);
            hr[1] = fmaxf(acc[i][1] + bv.y, 0.f);
            hr[2] = fmaxf(acc[i][2] + bv.z, 0.f);
            hr[3] = fmaxf(acc[i][3] + bv.w, 0.f);
        }
    }
    __syncthreads();

    // layer 2
    {
        float acc[4][4];
        #pragma unroll
        for (int i = 0; i < 4; ++i)
            #pragma unroll
            for (int j = 0; j < 4; ++j) acc[i][j] = 0.f;
        for (int d = 0; d < 128; ++d) {
            const float4 wv4 = *reinterpret_cast<const float4*>(Wo2 + d * 128 + cc * 4);
            #pragma unroll
            for (int i = 0; i < 4; ++i) {
                const float av = h_l[(rgp * 4 + i) * 129 + d];
                acc[i][0] = fmaf(av, wv4.x, acc[i][0]);
                acc[i][1] = fmaf(av, wv4.y, acc[i][1]);
                acc[i][2] = fmaf(av, wv4.z, acc[i][2]);
                acc[i][3] = fmaf(av, wv4.w, acc[i][3]);
            }
        }
        const float4 bv = *reinterpret_cast<const float4*>(bo2 + cc * 4);
        #pragma unroll
        for (int i = 0; i < 4; ++i) {
            float* pr = p2_l + (rgp * 4 + i) * 129 + cc * 4;
            pr[0] = fmaxf(acc[i][0] + bv.x, 0.f);
            pr[1] = fmaxf(acc[i][1] + bv.y, 0.f);
            pr[2] = fmaxf(acc[i][2] + bv.z, 0.f);
            pr[3] = fmaxf(acc[i][3] + bv.w, 0.f);
        }
    }
    __syncthreads();

    // layer 3 + residual + store (skip t == 255)
    if (tid < 128) {
        const int rr = tid >> 2;
        const int dd = tid & 3;
        float a0 = 0.f, a1 = 0.f, a2 = 0.f, a3 = 0.f;
        const float* pr = p2_l + rr * 129;
        for (int d = 0; d < 128; d += 4) {
            a0 = fmaf(pr[d + 0], Wo3[(d + 0) * 4 + dd], a0);
            a1 = fmaf(pr[d + 1], Wo3[(d + 1) * 4 + dd], a1);
            a2 = fmaf(pr[d + 2], Wo3[(d + 2) * 4 + dd], a2);
            a3 = fmaf(pr[d + 3], Wo3[(d + 3) * 4 + dd], a3);
        }
        const float pred = ((a0 + a1) + (a2 + a3)) + bo3[dd];
        if (t < 255) {
            out[((size_t)(b * 32 + rr) * 255 + t) * 4 + dd] = x_l[rr * 4 + dd] + pred;
        }
    }
}

__global__ void copy_relgraph(const float* __restrict__ g, float* __restrict__ out2)
{
    const int idx = blockIdx.x * 256 + threadIdx.x;
    if (idx < 15872) out2[idx] = g[idx % 1984];
}

extern "C" void kernel_launch(void* const* d_in, const int* in_sizes, int n_in,
                              void* d_out, int out_size, void* d_ws, size_t ws_size,
                              hipStream_t stream)
{
    (void)in_sizes; (void)n_in; (void)d_ws; (void)ws_size; (void)out_size;
    const float* inputs    = (const float*)d_in[0];
    const float* rel_graph = (const float*)d_in[3];
    const float* W1  = (const float*)d_in[4];
    const float* b1  = (const float*)d_in[5];
    const float* W2  = (const float*)d_in[6];
    const float* b2  = (const float*)d_in[7];
    const float* Wo1 = (const float*)d_in[8];
    const float* bo1 = (const float*)d_in[9];
    const float* Wo2 = (const float*)d_in[10];
    const float* bo2 = (const float*)d_in[11];
    const float* Wo3 = (const float*)d_in[12];
    const float* bo3 = (const float*)d_in[13];
    float* out = (float*)d_out;

    nri_fused<<<2048, 256, 0, stream>>>(inputs, rel_graph, W1, b1, W2, b2,
                                        Wo1, bo1, Wo2, bo2, Wo3, bo3, out);
    copy_relgraph<<<62, 256, 0, stream>>>(rel_graph, out + 261120);
}

// Round 6
// 258.174 us; speedup vs baseline: 3.4665x; 2.4226x over previous
//
#include <hip/hip_runtime.h>

// NRI MLP decoder, single step. B=8, N=32, T=256, D=4, E=992, K=2, H=64, M=64, NH=128.
// Edge e: receiver i=e/31, jj=e%31, sender j = jj<i ? jj : jj+1.
// h1 = relu(S[j]+R[i]), S = x@W1[k][0:4]+b1 (senders first), R = x@W1[k][4:8].
// msg = relu(h1@W2[k]+b2[k]); agg[i] += msg*g[e,k]
// aug=[agg|x|0pad] -> relu(@[Wo1_agg;Wo1_x]+bo1) -> relu(@Wo2+bo2) -> @Wo3+bo3; out=x+pred.
// All GEMMs via v_mfma_f32_16x16x32_f16 (fp32 accum, fp16 inputs via cvt_pkrtz).
// MFMA layout (16x16x32): A: row=l&15, k=8*(l>>4)+e (8 consecutive);
//                         B: col=l&15, k=8*(l>>4)+e; D: col=l&15, row=4*(l>>4)+reg.

typedef _Float16 f16x8 __attribute__((ext_vector_type(8)));
typedef __fp16   f16x2 __attribute__((ext_vector_type(2)));   // cvt_pkrtz return type
typedef float    f32x4 __attribute__((ext_vector_type(4)));

union ABfrag { f16x8 v; f16x2 h[4]; };

__global__ __launch_bounds__(256, 3)
void nri_fused(const float* __restrict__ inputs,
               const float* __restrict__ rgraph,
               const float* __restrict__ W1,  const float* __restrict__ b1,
               const float* __restrict__ W2,  const float* __restrict__ b2,
               const float* __restrict__ Wo1, const float* __restrict__ bo1,
               const float* __restrict__ Wo2, const float* __restrict__ bo2,
               const float* __restrict__ Wo3, const float* __restrict__ bo3,
               float* __restrict__ out)
{
    // floats: x 0(128) | g 128(1984) | S 2112(32x68) | R 4288(32x68) |
    //         aug 6464(32x100) | h_l 9664(32x136 halves = 2176 floats) = 11840 (47.4KB)
    // p2 overlays S/R: 2112(32x132=4224 <= 4352)
    __shared__ float smem[11840];
    float* x_l = smem;
    float* g_l = smem + 128;
    float* S   = smem + 2112;
    float* R   = smem + 4288;
    float* aug = smem + 6464;
    _Float16* h_l = reinterpret_cast<_Float16*>(smem + 9664);
    float* p2  = smem + 2112;

    const int tid  = threadIdx.x;
    const int b    = blockIdx.x >> 8;
    const int t    = blockIdx.x & 255;
    const int w    = tid >> 6;
    const int lane = tid & 63;
    const int q    = lane & 15;
    const int g4   = lane >> 4;

    // ---- stage x, g, aug x-part + zero pad (cols 64..95) ----
    if (tid < 32)
        reinterpret_cast<float4*>(x_l)[tid] =
            *reinterpret_cast<const float4*>(inputs + ((size_t)(b * 32 + tid) * 256 + t) * 4);
    for (int idx = tid; idx < 1984; idx += 256) g_l[idx] = rgraph[idx];
    for (int idx = tid; idx < 1024; idx += 256) {
        const int n = idx >> 5, c = idx & 31;
        aug[n * 100 + 64 + c] =
            (c < 4) ? inputs[((size_t)(b * 32 + n) * 256 + t) * 4 + c] : 0.f;
    }

    float agg_acc[8];
    #pragma unroll
    for (int rr = 0; rr < 8; ++rr) agg_acc[rr] = 0.f;

    for (int k = 0; k < 2; ++k) {
        __syncthreads();   // x_l ready (k=0); S/R free for restage (k=1)
        // ---- stage S (sender proj + b1), R (receiver proj), stride 68 ----
        for (int idx = tid; idx < 2048; idx += 256) {
            const int j = idx >> 6, kk = idx & 63;
            const float4 xj = reinterpret_cast<const float4*>(x_l)[j];
            const float* wp = W1 + k * 512 + kk;
            float s = b1[k * 64 + kk], r = 0.f;
            s = fmaf(xj.x, wp[0],   s);  r = fmaf(xj.x, wp[256], r);
            s = fmaf(xj.y, wp[64],  s);  r = fmaf(xj.y, wp[320], r);
            s = fmaf(xj.z, wp[128], s);  r = fmaf(xj.z, wp[384], r);
            s = fmaf(xj.w, wp[192], s);  r = fmaf(xj.w, wp[448], r);
            S[j * 68 + kk] = s;
            R[j * 68 + kk] = r;
        }
        // ---- W2 B-fragments + b2 (per lane, registers) ----
        ABfrag w2f[4][2];
        float bb[4];
        #pragma unroll
        for (int n = 0; n < 4; ++n) {
            bb[n] = b2[k * 64 + 16 * n + q];
            #pragma unroll
            for (int s = 0; s < 2; ++s)
                #pragma unroll
                for (int e2 = 0; e2 < 4; ++e2) {
                    const int ka = 32 * s + 8 * g4 + 2 * e2;
                    w2f[n][s].h[e2] = __builtin_amdgcn_cvt_pkrtz(
                        W2[k * 4096 + ka * 64 + 16 * n + q],
                        W2[k * 4096 + (ka + 1) * 64 + 16 * n + q]);
                }
        }
        __syncthreads();   // S,R visible

        // ---- per-receiver edge GEMM, no barriers ----
        #pragma unroll
        for (int rr = 0; rr < 8; ++rr) {
            const int i = w * 8 + rr;
            float4 Rv[2][2];
            #pragma unroll
            for (int s = 0; s < 2; ++s) {
                const float* rp = R + i * 68 + 32 * s + 8 * g4;
                Rv[s][0] = *reinterpret_cast<const float4*>(rp);
                Rv[s][1] = *reinterpret_cast<const float4*>(rp + 4);
            }
            ABfrag af[2][2];
            #pragma unroll
            for (int m = 0; m < 2; ++m) {
                const int r = 16 * m + q;
                const int j = (r == 31) ? 0 : ((r < i) ? r : r + 1);
                #pragma unroll
                for (int s = 0; s < 2; ++s) {
                    const float* sp = S + j * 68 + 32 * s + 8 * g4;
                    const float4 s0 = *reinterpret_cast<const float4*>(sp);
                    const float4 s1 = *reinterpret_cast<const float4*>(sp + 4);
                    af[m][s].h[0] = __builtin_amdgcn_cvt_pkrtz(
                        fmaxf(s0.x + Rv[s][0].x, 0.f), fmaxf(s0.y + Rv[s][0].y, 0.f));
                    af[m][s].h[1] = __builtin_amdgcn_cvt_pkrtz(
                        fmaxf(s0.z + Rv[s][0].z, 0.f), fmaxf(s0.w + Rv[s][0].w, 0.f));
                    af[m][s].h[2] = __builtin_amdgcn_cvt_pkrtz(
                        fmaxf(s1.x + Rv[s][1].x, 0.f), fmaxf(s1.y + Rv[s][1].y, 0.f));
                    af[m][s].h[3] = __builtin_amdgcn_cvt_pkrtz(
                        fmaxf(s1.z + Rv[s][1].z, 0.f), fmaxf(s1.w + Rv[s][1].w, 0.f));
                }
            }
            f32x4 acc[2][4];
            #pragma unroll
            for (int m = 0; m < 2; ++m)
                #pragma unroll
                for (int n = 0; n < 4; ++n) {
                    acc[m][n][0] = bb[n]; acc[m][n][1] = bb[n];
                    acc[m][n][2] = bb[n]; acc[m][n][3] = bb[n];
                }
            #pragma unroll
            for (int s = 0; s < 2; ++s)
                #pragma unroll
                for (int m = 0; m < 2; ++m)
                    #pragma unroll
                    for (int n = 0; n < 4; ++n)
                        acc[m][n] = __builtin_amdgcn_mfma_f32_16x16x32_f16(
                            af[m][s].v, w2f[n][s].v, acc[m][n], 0, 0, 0);
            float part[4] = {0.f, 0.f, 0.f, 0.f};
            #pragma unroll
            for (int m = 0; m < 2; ++m)
                #pragma unroll
                for (int reg = 0; reg < 4; ++reg) {
                    const int row = 16 * m + 4 * g4 + reg;
                    const float gv = (row < 31) ? g_l[(31 * i + row) * 2 + k] : 0.f;
                    #pragma unroll
                    for (int n = 0; n < 4; ++n)
                        part[n] = fmaf(fmaxf(acc[m][n][reg], 0.f), gv, part[n]);
                }
            #pragma unroll
            for (int n = 0; n < 4; ++n) {
                part[n] += __shfl_xor(part[n], 16);
                part[n] += __shfl_xor(part[n], 32);
            }
            const float v = (g4 == 0) ? part[0] : (g4 == 1) ? part[1]
                          : (g4 == 2) ? part[2] : part[3];
            agg_acc[rr] += v;
        }
    }

    // ---- agg -> aug cols 0..63 ----
    #pragma unroll
    for (int rr = 0; rr < 8; ++rr)
        aug[(w * 8 + rr) * 100 + 16 * g4 + q] = agg_acc[rr];
    __syncthreads();

    const int c0 = 32 * w;   // wave's 32-col slice of NH=128

    // ---- node layer 1: aug(32x96) @ [Wo1_agg;Wo1_x;0] -> h (fp16, stride 136) ----
    {
        ABfrag bf[2][3];
        #pragma unroll
        for (int n = 0; n < 2; ++n)
            #pragma unroll
            for (int s = 0; s < 3; ++s)
                #pragma unroll
                for (int e2 = 0; e2 < 4; ++e2) {
                    const int col = c0 + 16 * n + q;
                    const int ka = 32 * s + 8 * g4 + 2 * e2;
                    const int kb = ka + 1;
                    const float v0 = (ka < 64) ? Wo1[(4 + ka) * 128 + col]
                                   : ((ka < 68) ? Wo1[(ka - 64) * 128 + col] : 0.f);
                    const float v1 = (kb < 64) ? Wo1[(4 + kb) * 128 + col]
                                   : ((kb < 68) ? Wo1[(kb - 64) * 128 + col] : 0.f);
                    bf[n][s].h[e2] = __builtin_amdgcn_cvt_pkrtz(v0, v1);
                }
        f32x4 acc[2][2];
        #pragma unroll
        for (int m = 0; m < 2; ++m)
            #pragma unroll
            for (int n = 0; n < 2; ++n) {
                const float bv = bo1[c0 + 16 * n + q];
                acc[m][n][0] = bv; acc[m][n][1] = bv; acc[m][n][2] = bv; acc[m][n][3] = bv;
            }
        #pragma unroll
        for (int s = 0; s < 3; ++s) {
            ABfrag afr[2];
            #pragma unroll
            for (int m = 0; m < 2; ++m) {
                const float* ap = aug + (16 * m + q) * 100 + 32 * s + 8 * g4;
                const float4 a0 = *reinterpret_cast<const float4*>(ap);
                const float4 a1 = *reinterpret_cast<const float4*>(ap + 4);
                afr[m].h[0] = __builtin_amdgcn_cvt_pkrtz(a0.x, a0.y);
                afr[m].h[1] = __builtin_amdgcn_cvt_pkrtz(a0.z, a0.w);
                afr[m].h[2] = __builtin_amdgcn_cvt_pkrtz(a1.x, a1.y);
                afr[m].h[3] = __builtin_amdgcn_cvt_pkrtz(a1.z, a1.w);
            }
            #pragma unroll
            for (int m = 0; m < 2; ++m)
                #pragma unroll
                for (int n = 0; n < 2; ++n)
                    acc[m][n] = __builtin_amdgcn_mfma_f32_16x16x32_f16(
                        afr[m].v, bf[n][s].v, acc[m][n], 0, 0, 0);
        }
        #pragma unroll
        for (int m = 0; m < 2; ++m)
            #pragma unroll
            for (int n = 0; n < 2; ++n)
                #pragma unroll
                for (int reg = 0; reg < 4; ++reg) {
                    const int row = 16 * m + 4 * g4 + reg;
                    h_l[row * 136 + c0 + 16 * n + q] = (_Float16)fmaxf(acc[m][n][reg], 0.f);
                }
    }
    __syncthreads();

    // ---- node layer 2: h(32x128 fp16) @ Wo2 -> p2 (fp32, stride 132) ----
    {
        ABfrag bf[2][4];
        #pragma unroll
        for (int n = 0; n < 2; ++n)
            #pragma unroll
            for (int s = 0; s < 4; ++s)
                #pragma unroll
                for (int e2 = 0; e2 < 4; ++e2) {
                    const int col = c0 + 16 * n + q;
                    const int ka = 32 * s + 8 * g4 + 2 * e2;
                    bf[n][s].h[e2] = __builtin_amdgcn_cvt_pkrtz(
                        Wo2[ka * 128 + col], Wo2[(ka + 1) * 128 + col]);
                }
        f32x4 acc[2][2];
        #pragma unroll
        for (int m = 0; m < 2; ++m)
            #pragma unroll
            for (int n = 0; n < 2; ++n) {
                const float bv = bo2[c0 + 16 * n + q];
                acc[m][n][0] = bv; acc[m][n][1] = bv; acc[m][n][2] = bv; acc[m][n][3] = bv;
            }
        #pragma unroll
        for (int s = 0; s < 4; ++s) {
            f16x8 afr[2];
            #pragma unroll
            for (int m = 0; m < 2; ++m)
                afr[m] = *reinterpret_cast<const f16x8*>(
                    h_l + (16 * m + q) * 136 + 32 * s + 8 * g4);
            #pragma unroll
            for (int m = 0; m < 2; ++m)
                #pragma unroll
                for (int n = 0; n < 2; ++n)
                    acc[m][n] = __builtin_amdgcn_mfma_f32_16x16x32_f16(
                        afr[m], bf[n][s].v, acc[m][n], 0, 0, 0);
        }
        #pragma unroll
        for (int m = 0; m < 2; ++m)
            #pragma unroll
            for (int n = 0; n < 2; ++n)
                #pragma unroll
                for (int reg = 0; reg < 4; ++reg) {
                    const int row = 16 * m + 4 * g4 + reg;
                    p2[row * 132 + c0 + 16 * n + q] = fmaxf(acc[m][n][reg], 0.f);
                }
    }
    __syncthreads();

    // ---- layer 3 (fp32 VALU) + residual + store (skip t == 255) ----
    if (tid < 128) {
        const int rr3 = tid >> 2;
        const int dd  = tid & 3;
        float a0 = 0.f, a1 = 0.f, a2 = 0.f, a3 = 0.f;
        const float* pr = p2 + rr3 * 132;
        for (int d = 0; d < 128; d += 4) {
            a0 = fmaf(pr[d + 0], Wo3[(d + 0) * 4 + dd], a0);
            a1 = fmaf(pr[d + 1], Wo3[(d + 1) * 4 + dd], a1);
            a2 = fmaf(pr[d + 2], Wo3[(d + 2) * 4 + dd], a2);
            a3 = fmaf(pr[d + 3], Wo3[(d + 3) * 4 + dd], a3);
        }
        const float pred = ((a0 + a1) + (a2 + a3)) + bo3[dd];
        if (t < 255) {
            out[((size_t)(b * 32 + rr3) * 255 + t) * 4 + dd] = x_l[rr3 * 4 + dd] + pred;
        }
    }
}

__global__ void copy_relgraph(const float* __restrict__ g, float* __restrict__ out2)
{
    const int idx = blockIdx.x * 256 + threadIdx.x;
    if (idx < 15872) out2[idx] = g[idx % 1984];
}

extern "C" void kernel_launch(void* const* d_in, const int* in_sizes, int n_in,
                              void* d_out, int out_size, void* d_ws, size_t ws_size,
                              hipStream_t stream)
{
    (void)in_sizes; (void)n_in; (void)d_ws; (void)ws_size; (void)out_size;
    const float* inputs    = (const float*)d_in[0];
    const float* rel_graph = (const float*)d_in[3];
    const float* W1  = (const float*)d_in[4];
    const float* b1  = (const float*)d_in[5];
    const float* W2  = (const float*)d_in[6];
    const float* b2  = (const float*)d_in[7];
    const float* Wo1 = (const float*)d_in[8];
    const float* bo1 = (const float*)d_in[9];
    const float* Wo2 = (const float*)d_in[10];
    const float* bo2 = (const float*)d_in[11];
    const float* Wo3 = (const float*)d_in[12];
    const float* bo3 = (const float*)d_in[13];
    float* out = (float*)d_out;

    nri_fused<<<2048, 256, 0, stream>>>(inputs, rel_graph, W1, b1, W2, b2,
                                        Wo1, bo1, Wo2, bo2, Wo3, bo3, out);
    copy_relgraph<<<62, 256, 0, stream>>>(rel_graph, out + 261120);
}